// Round 11
// baseline (485.842 us; speedup 1.0000x reference)
//
#include <hip/hip_runtime.h>

#define NB 512
#define NT 1024
#define NK 48
#define NEGV -10000.0f
#define S_START 46
#define S_END 47
#define NCH 32            // 32-step windows (chunks)
#define CLEN 32

__device__ __forceinline__ float rfl_f32(float x) {
    return __int_as_float(__builtin_amdgcn_readfirstlane(__float_as_int(x)));
}

// 4 waves/block, lockstep-barrier pipeline (34 __syncthreads per wave).
// role0: CRF forward in the EXP DOMAIN (exact pow2 renorm via exponent
//   bits; no log on the serial chain). role1: value-only Viterbi sweep +
//   checkpoint ring + epilogue. role2/3: replay chunk c over windows
//   c,c+1 (FULL argmax, bit-identical backpointers), bp + comp.
// R11 change vs R10: s_setprio(1) on the two serial-critical producer
// waves (roles 0,1) — CU scheduler favors their issue over the
// latency-tolerant replay consumers (T5 regime: genuine role split).
extern "C" __global__ __launch_bounds__(256, 1)
void crf_fused(const float* __restrict__ feats, const float* __restrict__ trans,
               float* __restrict__ out)
{
    __shared__ unsigned char bp[NT * NK];        // 48 KB backpointers
    __shared__ float ckpt[4 * NK];               // 4-slot chunk-entry ring
    __shared__ unsigned char comp[NCH * NK];     // composed chunk maps
    __shared__ unsigned char boundary[NCH];
    __shared__ float eabuf[64];                  // fwd broadcast
    __shared__ float vbuf1[64];                  // sweep broadcast
    __shared__ float vbufw[2][64];               // replay broadcast per wave

    const int b = blockIdx.x;
    const int wave = threadIdx.x >> 6;
    const int role = (wave + b) & 3;
    const int lane = threadIdx.x & 63;
    const bool act = lane < NK;
    const int LL = act ? lane : (NK - 1);        // lanes 48..63 mirror 47
    const float* f = feats + (size_t)b * NT * NK;
    const float* fb = f + LL;

    if (role <= 1) __builtin_amdgcn_s_setprio(1);    // producers get priority

    float tEnd = NEGV;
    if (act && lane != S_END) tEnd = trans[S_END * NK + lane];

    if (role == 0) {
        // ---------------- forward, exp-domain state
        float Erow[NK];
        {
            const bool rowdead = (lane == S_START);
            const float4* r4 = (const float4*)(trans + LL * NK);
            #pragma unroll
            for (int q = 0; q < NK / 4; ++q) {
                float4 r = r4[q];
                const int c = 4 * q;
                Erow[c + 0] = (rowdead || c + 0 == S_END) ? 0.0f : __expf(r.x);
                Erow[c + 1] = (rowdead || c + 1 == S_END) ? 0.0f : __expf(r.y);
                Erow[c + 2] = (rowdead || c + 2 == S_END) ? 0.0f : __expf(r.z);
                Erow[c + 3] = (rowdead || c + 3 == S_END) ? 0.0f : __expf(r.w);
            }
        }
        float ea = (lane == S_START) ? 1.0f : 0.0f;  // exp(alpha - M), anchored
        int Etot = 0;                                // exact binary exponent shift
        eabuf[lane] = ea;
        __builtin_amdgcn_wave_barrier();
        float fr0 = fb[0 * NK], fr1 = fb[1 * NK], fr2 = fb[2 * NK], fr3 = fb[3 * NK];

        auto fstep = [&](float fc) {
            float ef = __expf(fc);               // OFF-chain: fc ready 4 steps early
            float eav[NK];
            {
                const float4* e4 = (const float4*)eabuf;
                #pragma unroll
                for (int q = 0; q < NK / 4; ++q) {
                    float4 r = e4[q];
                    eav[4 * q + 0] = r.x; eav[4 * q + 1] = r.y;
                    eav[4 * q + 2] = r.z; eav[4 * q + 3] = r.w;
                }
            }
            float a0 = 0.f, a1 = 0.f, a2 = 0.f, a3 = 0.f;
            #pragma unroll
            for (int p = 0; p < NK; p += 4) {
                a0 = fmaf(Erow[p + 0], eav[p + 0], a0);
                a1 = fmaf(Erow[p + 1], eav[p + 1], a1);
                a2 = fmaf(Erow[p + 2], eav[p + 2], a2);
                a3 = fmaf(Erow[p + 3], eav[p + 3], a3);
            }
            float acc = (a0 + a1) + (a2 + a3);   // lane0: >0 always (ea[0]~1)
            float nv = acc * ef;                 // dead row: acc==0 -> stays 0
            float nvr = rfl_f32(nv);             // lane-0 value, positive normal
            int e = ((__float_as_int(nvr) >> 23) & 255) - 127;
            Etot += e;                           // exact integer accumulation
            float sc = __int_as_float((127 - e) << 23);  // exact 2^-e
            ea = nv * sc;                        // lane-0 back to [1,2)
            __builtin_amdgcn_wave_barrier();
            eabuf[lane] = ea;
            __builtin_amdgcn_wave_barrier();
        };

        __syncthreads();                                     // B0
        for (int it = 0; it <= NCH; ++it) {
            if (it < NCH) {
                for (int g = 0; g < CLEN / 4; ++g) {
                    const int t = it * CLEN + 4 * g;
                    { float fc = fr0; int nr = (t + 4 < NT) ? t + 4 : NT - 1; fr0 = fb[nr * NK]; fstep(fc); }
                    { float fc = fr1; int nr = (t + 5 < NT) ? t + 5 : NT - 1; fr1 = fb[nr * NK]; fstep(fc); }
                    { float fc = fr2; int nr = (t + 6 < NT) ? t + 6 : NT - 1; fr2 = fb[nr * NK]; fstep(fc); }
                    { float fc = fr3; int nr = (t + 7 < NT) ? t + 7 : NT - 1; fr3 = fb[nr * NK]; fstep(fc); }
                }
            }
            __syncthreads();                                 // B1..B33
        }
        // logZ = Etot*ln2 + logsumexp(log(ea) + tEnd)
        float u = __logf(ea);                    // ea==0 -> -inf (dead lanes)
        float x = act ? (u + tEnd) : -INFINITY;
        float M2 = x;
        #pragma unroll
        for (int off = 32; off >= 1; off >>= 1)
            M2 = fmaxf(M2, __shfl_xor(M2, off, 64));
        float es = __expf(x - M2);
        #pragma unroll
        for (int off = 32; off >= 1; off >>= 1)
            es += __shfl_xor(es, off, 64);
        if (lane == 0)
            out[b] = (float)Etot * 0.6931471805599453f + M2 + __logf(es);
    } else if (role == 1) {
        // ---------------- producer: value-only sweep + checkpoint ring
        float trow[NK];
        {
            const bool rowdead = (lane == S_START);
            const float4* r4 = (const float4*)(trans + LL * NK);
            #pragma unroll
            for (int q = 0; q < NK / 4; ++q) {
                float4 r = r4[q];
                const int c = 4 * q;
                trow[c + 0] = (rowdead || c + 0 == S_END) ? NEGV : r.x;
                trow[c + 1] = (rowdead || c + 1 == S_END) ? NEGV : r.y;
                trow[c + 2] = (rowdead || c + 2 == S_END) ? NEGV : r.z;
                trow[c + 3] = (rowdead || c + 3 == S_END) ? NEGV : r.w;
            }
        }
        float v = (lane == S_START) ? 0.0f : NEGV;
        vbuf1[lane] = v;
        if (act) ckpt[0 * NK + lane] = v;                    // chunk-0 entry
        __builtin_amdgcn_wave_barrier();
        float fr0 = fb[0 * NK], fr1 = fb[1 * NK], fr2 = fb[2 * NK], fr3 = fb[3 * NK];

        auto vstep = [&](float fc) {
            float s[NK];
            {
                const float4* v4 = (const float4*)vbuf1;
                #pragma unroll
                for (int q = 0; q < NK / 4; ++q) {
                    float4 r = v4[q];
                    s[4 * q + 0] = r.x + trow[4 * q + 0];
                    s[4 * q + 1] = r.y + trow[4 * q + 1];
                    s[4 * q + 2] = r.z + trow[4 * q + 2];
                    s[4 * q + 3] = r.w + trow[4 * q + 3];
                }
            }
            float m16[16];
            #pragma unroll
            for (int i = 0; i < 16; ++i)
                m16[i] = fmaxf(fmaxf(s[3 * i], s[3 * i + 1]), s[3 * i + 2]);
            float m6[6];
            #pragma unroll
            for (int i = 0; i < 5; ++i)
                m6[i] = fmaxf(fmaxf(m16[3 * i], m16[3 * i + 1]), m16[3 * i + 2]);
            m6[5] = m16[15];
            float best = fmaxf(fmaxf(fmaxf(m6[0], m6[1]), m6[2]),
                               fmaxf(fmaxf(m6[3], m6[4]), m6[5]));
            v = best + fc;                                   // +feat after max
            __builtin_amdgcn_wave_barrier();
            vbuf1[lane] = v;
            __builtin_amdgcn_wave_barrier();
        };

        int last = 0;
        __syncthreads();                                     // B0
        for (int it = 0; it <= NCH; ++it) {
            if (it < NCH) {
                for (int g = 0; g < CLEN / 4; ++g) {
                    const int t = it * CLEN + 4 * g;
                    { float fc = fr0; int nr = (t + 4 < NT) ? t + 4 : NT - 1; fr0 = fb[nr * NK]; vstep(fc); }
                    { float fc = fr1; int nr = (t + 5 < NT) ? t + 5 : NT - 1; fr1 = fb[nr * NK]; vstep(fc); }
                    { float fc = fr2; int nr = (t + 6 < NT) ? t + 6 : NT - 1; fr2 = fb[nr * NK]; vstep(fc); }
                    { float fc = fr3; int nr = (t + 7 < NT) ? t + 7 : NT - 1; fr3 = fb[nr * NK]; vstep(fc); }
                }
                // v is now the entry state of chunk it+1 -> ring slot
                if (act && it + 1 < NCH) ckpt[((it + 1) & 3) * NK + lane] = v;
            } else {
                // termination: first-occurrence argmax of v + trans[END]
                float xv = act ? (v + tEnd) : -INFINITY;
                int idx = act ? lane : 63;
                float val = xv;
                #pragma unroll
                for (int off = 32; off >= 1; off >>= 1) {
                    float ov = __shfl_xor(val, off, 64);
                    int   oi = __shfl_xor(idx, off, 64);
                    if (ov > val || (ov == val && oi < idx)) { val = ov; idx = oi; }
                }
                if (lane == 0) out[NB + b] = val;
                last = idx;
            }
            __syncthreads();                                 // B1..B33
        }
        // epilogue: chase + expansion (bp/comp complete after final barrier)
        if (lane == 0) {
            int tag = last;
            for (int l = NCH - 1; l >= 0; --l) {
                boundary[l] = (unsigned char)tag;
                tag = comp[l * NK + tag];
            }
        }
        __builtin_amdgcn_wave_barrier();
        if (lane < NCH) {
            int tag = boundary[lane];                        // lane = chunk
            float* pout = out + 2 * NB + (size_t)b * NT;
            const int tbase = lane * CLEN;
            for (int i = CLEN - 1; i >= 0; --i) {
                pout[tbase + i] = (float)tag;
                tag = bp[(tbase + i) * NK + tag];
            }
        }
    } else {
        // ---------------- consumers: replay chunk c over windows c, c+1
        const int w = role - 2;                              // 0: even, 1: odd
        float trow[NK];
        {
            const bool rowdead = (lane == S_START);
            const float4* r4 = (const float4*)(trans + LL * NK);
            #pragma unroll
            for (int q = 0; q < NK / 4; ++q) {
                float4 r = r4[q];
                const int c = 4 * q;
                trow[c + 0] = (rowdead || c + 0 == S_END) ? NEGV : r.x;
                trow[c + 1] = (rowdead || c + 1 == S_END) ? NEGV : r.y;
                trow[c + 2] = (rowdead || c + 2 == S_END) ? NEGV : r.z;
                trow[c + 3] = (rowdead || c + 3 == S_END) ? NEGV : r.w;
            }
        }
        float* vbw = vbufw[w];
        const int big = 63;
        int bpl[16], bph[16];

        // 16 replay steps [base, base+16) of chunk c; ba statically indexed
        auto replay16 = [&](int c, int base, int* ba) {
            const float* fbc = fb + (size_t)c * CLEN * NK;
            unsigned char* bpc = bp + (size_t)c * CLEN * NK;
            float fv[16];
            #pragma unroll
            for (int i = 0; i < 16; ++i) fv[i] = fbc[(base + i) * NK];
            #pragma unroll
            for (int i = 0; i < 16; ++i) {
                float s[NK];
                {
                    const float4* v4 = (const float4*)vbw;
                    #pragma unroll
                    for (int q = 0; q < NK / 4; ++q) {
                        float4 r = v4[q];
                        s[4 * q + 0] = r.x + trow[4 * q + 0];
                        s[4 * q + 1] = r.y + trow[4 * q + 1];
                        s[4 * q + 2] = r.z + trow[4 * q + 2];
                        s[4 * q + 3] = r.w + trow[4 * q + 3];
                    }
                }
                float m16[16];
                #pragma unroll
                for (int j = 0; j < 16; ++j)
                    m16[j] = fmaxf(fmaxf(s[3 * j], s[3 * j + 1]), s[3 * j + 2]);
                float m6[6];
                #pragma unroll
                for (int j = 0; j < 5; ++j)
                    m6[j] = fmaxf(fmaxf(m16[3 * j], m16[3 * j + 1]), m16[3 * j + 2]);
                m6[5] = m16[15];
                float best = fmaxf(fmaxf(fmaxf(m6[0], m6[1]), m6[2]),
                                   fmaxf(fmaxf(m6[3], m6[4]), m6[5]));
                // first-occurrence argmax: chained select per 3-wide group
                int n16[16];
                #pragma unroll
                for (int j = 0; j < 16; ++j) {
                    int r = (s[3 * j + 2] == best) ? 3 * j + 2 : big;
                    r = (s[3 * j + 1] == best) ? 3 * j + 1 : r;
                    r = (s[3 * j + 0] == best) ? 3 * j + 0 : r;
                    n16[j] = r;
                }
                int n6[6];
                #pragma unroll
                for (int j = 0; j < 5; ++j)
                    n6[j] = min(min(n16[3 * j], n16[3 * j + 1]), n16[3 * j + 2]);
                n6[5] = n16[15];
                int bi = min(min(min(n6[0], n6[1]), n6[2]),
                             min(min(n6[3], n6[4]), n6[5]));

                ba[i] = bi;
                bpc[(base + i) * NK + LL] = (unsigned char)bi;
                float vn = best + fv[i];                     // +feat after argmax
                __builtin_amdgcn_wave_barrier();
                vbw[lane] = vn;
                __builtin_amdgcn_wave_barrier();
            }
        };

        __syncthreads();                                     // B0
        for (int it = 0; it <= NCH; ++it) {
            if (it < NCH && (it & 1) == w) {
                // start chunk c = it (ckpt[c] published during window it-1)
                vbw[lane] = ckpt[(it & 3) * NK + LL];
                __builtin_amdgcn_wave_barrier();
                replay16(it, 0, bpl);
            } else if (it >= 1 && ((it - 1) & 1) == w) {
                // finish chunk c = it-1, then compose its tag-map
                const int c = it - 1;
                replay16(c, 16, bph);
                int tag = act ? lane : 0;
                #pragma unroll
                for (int i = 15; i >= 0; --i)
                    tag = __builtin_amdgcn_ds_bpermute(tag << 2, bph[i]);
                #pragma unroll
                for (int i = 15; i >= 0; --i)
                    tag = __builtin_amdgcn_ds_bpermute(tag << 2, bpl[i]);
                if (act) comp[c * NK + lane] = (unsigned char)tag;
            }
            __syncthreads();                                 // B1..B33
        }
    }
}

extern "C" void kernel_launch(void* const* d_in, const int* in_sizes, int n_in,
                              void* d_out, int out_size, void* d_ws, size_t ws_size,
                              hipStream_t stream) {
    (void)in_sizes; (void)n_in; (void)d_ws; (void)ws_size; (void)out_size;
    const float* feats = (const float*)d_in[0];
    const float* trans = (const float*)d_in[1];
    float* out = (float*)d_out;
    crf_fused<<<dim3(NB), dim3(256), 0, stream>>>(feats, trans, out);
}

// Round 13
// 456.686 us; speedup vs baseline: 1.0638x; 1.0638x over previous
//
#include <hip/hip_runtime.h>

#define NB 512
#define NT 1024
#define NK 48
#define NEGV -10000.0f
#define S_START 46
#define S_END 47
#define NCH 32            // 32-step windows (chunks)
#define CLEN 32
#define RING 128          // vhist/bhist ring (4 windows: race-free margin)

#define WS_BP_SZ ((size_t)NB * NT * NK)   // 24,117,248 B backpointers

__device__ __forceinline__ float rfl_f32(float x) {
    return __int_as_float(__builtin_amdgcn_readfirstlane(__float_as_int(x)));
}

// 4 waves/block, lockstep pipeline, 35 uniform __syncthreads per wave.
// role0: CRF forward, exp-domain (exact pow2 renorm; absmax 0.0 verified).
// role1: Viterbi value sweep; publishes v_t -> vhist[t&127] and the
//        pre-emission tree max best_t -> bhist[t&127] (off-chain writes).
// role2/3: CHAIN-FREE replay: for each step t of chunk c=it-1 (16 steps
//        per wave, all independent): s[p]=vhist[t-1][p]+trow[p] (identical
//        adds -> identical fp32 values) and best=bhist[t][n] (bit-identical
//        tree result) -> first-occurrence argmax == verified R0 semantics.
//        bp bytes -> global ws; bp also -> small LDS ring for compose.
//        role2 additionally composes chunk it-2's tag-map via ds_bpermute.
// role1 epilogue: boundary chase over comp + path expansion (bp from ws).
extern "C" __global__ __launch_bounds__(256, 1)
void crf_pipe(const float* __restrict__ feats, const float* __restrict__ trans,
              float* __restrict__ out, unsigned char* __restrict__ ws)
{
    __shared__ __align__(16) float vhist[RING][NK];   // 24 KB v history ring
    __shared__ __align__(16) float bhist[RING][NK];   // 24 KB best history ring
    __shared__ unsigned char bpring[2][CLEN][64];     // 4 KB bp compose ring
    __shared__ unsigned char comp[NCH * NK];          // composed chunk maps
    __shared__ unsigned char boundary[NCH];
    __shared__ float eabuf[64];                       // fwd broadcast

    const int b = blockIdx.x;
    const int wave = threadIdx.x >> 6;
    const int role = (wave + b) & 3;
    const int lane = threadIdx.x & 63;
    const bool act = lane < NK;
    const int LL = act ? lane : (NK - 1);             // lanes 48..63 mirror 47
    const float* f = feats + (size_t)b * NT * NK;
    const float* fb = f + LL;
    unsigned char* bpg = ws + (size_t)b * NT * NK;

    float tEnd = NEGV;
    if (act && lane != S_END) tEnd = trans[S_END * NK + lane];

    if (role == 0) {
        // ---------------- forward, exp-domain state (unchanged from R10)
        float Erow[NK];
        {
            const bool rowdead = (lane == S_START);
            const float4* r4 = (const float4*)(trans + LL * NK);
            #pragma unroll
            for (int q = 0; q < NK / 4; ++q) {
                float4 r = r4[q];
                const int c = 4 * q;
                Erow[c + 0] = (rowdead || c + 0 == S_END) ? 0.0f : __expf(r.x);
                Erow[c + 1] = (rowdead || c + 1 == S_END) ? 0.0f : __expf(r.y);
                Erow[c + 2] = (rowdead || c + 2 == S_END) ? 0.0f : __expf(r.z);
                Erow[c + 3] = (rowdead || c + 3 == S_END) ? 0.0f : __expf(r.w);
            }
        }
        float ea = (lane == S_START) ? 1.0f : 0.0f;
        int Etot = 0;
        eabuf[lane] = ea;
        __builtin_amdgcn_wave_barrier();
        float fr0 = fb[0 * NK], fr1 = fb[1 * NK], fr2 = fb[2 * NK], fr3 = fb[3 * NK];

        auto fstep = [&](float fc) {
            float ef = __expf(fc);
            float eav[NK];
            {
                const float4* e4 = (const float4*)eabuf;
                #pragma unroll
                for (int q = 0; q < NK / 4; ++q) {
                    float4 r = e4[q];
                    eav[4 * q + 0] = r.x; eav[4 * q + 1] = r.y;
                    eav[4 * q + 2] = r.z; eav[4 * q + 3] = r.w;
                }
            }
            float a0 = 0.f, a1 = 0.f, a2 = 0.f, a3 = 0.f;
            #pragma unroll
            for (int p = 0; p < NK; p += 4) {
                a0 = fmaf(Erow[p + 0], eav[p + 0], a0);
                a1 = fmaf(Erow[p + 1], eav[p + 1], a1);
                a2 = fmaf(Erow[p + 2], eav[p + 2], a2);
                a3 = fmaf(Erow[p + 3], eav[p + 3], a3);
            }
            float acc = (a0 + a1) + (a2 + a3);
            float nv = acc * ef;
            float nvr = rfl_f32(nv);
            int e = ((__float_as_int(nvr) >> 23) & 255) - 127;
            Etot += e;
            float sc = __int_as_float((127 - e) << 23);
            ea = nv * sc;
            __builtin_amdgcn_wave_barrier();
            eabuf[lane] = ea;
            __builtin_amdgcn_wave_barrier();
        };

        __syncthreads();                                     // B0
        for (int it = 0; it <= NCH + 1; ++it) {
            if (it < NCH) {
                for (int g = 0; g < CLEN / 4; ++g) {
                    const int t = it * CLEN + 4 * g;
                    { float fc = fr0; int nr = (t + 4 < NT) ? t + 4 : NT - 1; fr0 = fb[nr * NK]; fstep(fc); }
                    { float fc = fr1; int nr = (t + 5 < NT) ? t + 5 : NT - 1; fr1 = fb[nr * NK]; fstep(fc); }
                    { float fc = fr2; int nr = (t + 6 < NT) ? t + 6 : NT - 1; fr2 = fb[nr * NK]; fstep(fc); }
                    { float fc = fr3; int nr = (t + 7 < NT) ? t + 7 : NT - 1; fr3 = fb[nr * NK]; fstep(fc); }
                }
            }
            __syncthreads();                                 // B1..B34
        }
        float u = __logf(ea);
        float x = act ? (u + tEnd) : -INFINITY;
        float M2 = x;
        #pragma unroll
        for (int off = 32; off >= 1; off >>= 1)
            M2 = fmaxf(M2, __shfl_xor(M2, off, 64));
        float es = __expf(x - M2);
        #pragma unroll
        for (int off = 32; off >= 1; off >>= 1)
            es += __shfl_xor(es, off, 64);
        if (lane == 0)
            out[b] = (float)Etot * 0.6931471805599453f + M2 + __logf(es);
    } else if (role == 1) {
        // ---------------- sweep: value chain + history publication
        float trow[NK];
        {
            const bool rowdead = (lane == S_START);
            const float4* r4 = (const float4*)(trans + LL * NK);
            #pragma unroll
            for (int q = 0; q < NK / 4; ++q) {
                float4 r = r4[q];
                const int c = 4 * q;
                trow[c + 0] = (rowdead || c + 0 == S_END) ? NEGV : r.x;
                trow[c + 1] = (rowdead || c + 1 == S_END) ? NEGV : r.y;
                trow[c + 2] = (rowdead || c + 2 == S_END) ? NEGV : r.z;
                trow[c + 3] = (rowdead || c + 3 == S_END) ? NEGV : r.w;
            }
        }
        float v = (lane == S_START) ? 0.0f : NEGV;
        if (act) vhist[RING - 1][lane] = v;              // v_{-1} slot
        __builtin_amdgcn_wave_barrier();
        float fr0 = fb[0 * NK], fr1 = fb[1 * NK], fr2 = fb[2 * NK], fr3 = fb[3 * NK];

        auto vstep = [&](float fc, int t) {
            float s[NK];
            {
                const float4* v4 = (const float4*)vhist[(t - 1) & (RING - 1)];
                #pragma unroll
                for (int q = 0; q < NK / 4; ++q) {
                    float4 r = v4[q];
                    s[4 * q + 0] = r.x + trow[4 * q + 0];
                    s[4 * q + 1] = r.y + trow[4 * q + 1];
                    s[4 * q + 2] = r.z + trow[4 * q + 2];
                    s[4 * q + 3] = r.w + trow[4 * q + 3];
                }
            }
            float m16[16];
            #pragma unroll
            for (int i = 0; i < 16; ++i)
                m16[i] = fmaxf(fmaxf(s[3 * i], s[3 * i + 1]), s[3 * i + 2]);
            float m6[6];
            #pragma unroll
            for (int i = 0; i < 5; ++i)
                m6[i] = fmaxf(fmaxf(m16[3 * i], m16[3 * i + 1]), m16[3 * i + 2]);
            m6[5] = m16[15];
            float best = fmaxf(fmaxf(fmaxf(m6[0], m6[1]), m6[2]),
                               fmaxf(fmaxf(m6[3], m6[4]), m6[5]));
            v = best + fc;                               // +feat after max
            __builtin_amdgcn_wave_barrier();
            if (act) {
                vhist[t & (RING - 1)][lane] = v;
                bhist[t & (RING - 1)][lane] = best;      // exact tree result
            }
            __builtin_amdgcn_wave_barrier();
        };

        int last = 0;
        __syncthreads();                                     // B0
        for (int it = 0; it <= NCH + 1; ++it) {
            if (it < NCH) {
                for (int g = 0; g < CLEN / 4; ++g) {
                    const int t = it * CLEN + 4 * g;
                    { float fc = fr0; int nr = (t + 4 < NT) ? t + 4 : NT - 1; fr0 = fb[nr * NK]; vstep(fc, t + 0); }
                    { float fc = fr1; int nr = (t + 5 < NT) ? t + 5 : NT - 1; fr1 = fb[nr * NK]; vstep(fc, t + 1); }
                    { float fc = fr2; int nr = (t + 6 < NT) ? t + 6 : NT - 1; fr2 = fb[nr * NK]; vstep(fc, t + 2); }
                    { float fc = fr3; int nr = (t + 7 < NT) ? t + 7 : NT - 1; fr3 = fb[nr * NK]; vstep(fc, t + 3); }
                }
            } else if (it == NCH) {
                // termination: first-occurrence argmax of v + trans[END]
                float xv = act ? (v + tEnd) : -INFINITY;
                int idx = act ? lane : 63;
                float val = xv;
                #pragma unroll
                for (int off = 32; off >= 1; off >>= 1) {
                    float ov = __shfl_xor(val, off, 64);
                    int   oi = __shfl_xor(idx, off, 64);
                    if (ov > val || (ov == val && oi < idx)) { val = ov; idx = oi; }
                }
                if (lane == 0) out[NB + b] = val;
                last = idx;
            }
            __syncthreads();                                 // B1..B34
        }
        // epilogue: chase over comp, then expansion from global bp
        if (lane == 0) {
            int tag = last;
            for (int l = NCH - 1; l >= 0; --l) {
                boundary[l] = (unsigned char)tag;
                tag = comp[l * NK + tag];
            }
        }
        __builtin_amdgcn_wave_barrier();
        if (lane < NCH) {
            int tag = boundary[lane];                        // lane = chunk
            float* pout = out + 2 * NB + (size_t)b * NT;
            const int tbase = lane * CLEN;
            for (int i = CLEN - 1; i >= 0; --i) {
                pout[tbase + i] = (float)tag;
                tag = bpg[(size_t)(tbase + i) * NK + tag];
            }
        }
    } else {
        // ---------------- chain-free replay (role2: lo half + compose duty;
        // role3: hi half). All 16 steps independent: no propagate, no
        // internal barriers, no feats.
        const int off = (role - 2) * 16;
        float trow[NK];
        {
            const bool rowdead = (lane == S_START);
            const float4* r4 = (const float4*)(trans + LL * NK);
            #pragma unroll
            for (int q = 0; q < NK / 4; ++q) {
                float4 r = r4[q];
                const int c = 4 * q;
                trow[c + 0] = (rowdead || c + 0 == S_END) ? NEGV : r.x;
                trow[c + 1] = (rowdead || c + 1 == S_END) ? NEGV : r.y;
                trow[c + 2] = (rowdead || c + 2 == S_END) ? NEGV : r.z;
                trow[c + 3] = (rowdead || c + 3 == S_END) ? NEGV : r.w;
            }
        }
        const int big = 63;

        auto replay16 = [&](int c) {
            #pragma unroll
            for (int i = 0; i < 16; ++i) {
                const int t = c * CLEN + off + i;
                float s[NK];
                {
                    const float4* v4 = (const float4*)vhist[(t - 1) & (RING - 1)];
                    #pragma unroll
                    for (int q = 0; q < NK / 4; ++q) {
                        float4 r = v4[q];
                        s[4 * q + 0] = r.x + trow[4 * q + 0];
                        s[4 * q + 1] = r.y + trow[4 * q + 1];
                        s[4 * q + 2] = r.z + trow[4 * q + 2];
                        s[4 * q + 3] = r.w + trow[4 * q + 3];
                    }
                }
                float best = bhist[t & (RING - 1)][LL];  // exact sweep max
                int n16[16];
                #pragma unroll
                for (int j = 0; j < 16; ++j) {
                    int r = (s[3 * j + 2] == best) ? 3 * j + 2 : big;
                    r = (s[3 * j + 1] == best) ? 3 * j + 1 : r;
                    r = (s[3 * j + 0] == best) ? 3 * j + 0 : r;
                    n16[j] = r;
                }
                int n6[6];
                #pragma unroll
                for (int j = 0; j < 5; ++j)
                    n6[j] = min(min(n16[3 * j], n16[3 * j + 1]), n16[3 * j + 2]);
                n6[5] = n16[15];
                int bi = min(min(min(n6[0], n6[1]), n6[2]),
                             min(min(n6[3], n6[4]), n6[5]));

                bpring[c & 1][off + i][LL] = (unsigned char)bi;
                bpg[(size_t)t * NK + LL] = (unsigned char)bi;
            }
        };

        __syncthreads();                                     // B0
        for (int it = 0; it <= NCH + 1; ++it) {
            if (it >= 1 && it <= NCH) replay16(it - 1);
            if (role == 2 && it >= 2) {
                // compose chunk c = it-2 (bpring halves complete + barrier'd)
                const int c = it - 2;
                int r[CLEN];
                #pragma unroll
                for (int i = 0; i < CLEN; ++i)
                    r[i] = bpring[c & 1][i][lane];
                int tag = act ? lane : 0;
                #pragma unroll
                for (int i = CLEN - 1; i >= 0; --i)
                    tag = __builtin_amdgcn_ds_bpermute(tag << 2, r[i]);
                if (act) comp[c * NK + lane] = (unsigned char)tag;
            }
            __syncthreads();                                 // B1..B34
        }
    }
}

// =====================================================================
// Fallback (no workspace): proven single-kernel version (R5, 447 us).
// =====================================================================
extern "C" __global__ __launch_bounds__(128, 1)
void crf_fused_fb(const float* __restrict__ feats, const float* __restrict__ trans,
                  float* __restrict__ out)
{
    __shared__ unsigned char bp[NT * NK];
    __shared__ unsigned char comp[64 * NK];
    __shared__ unsigned char boundary[64];
    __shared__ float eabuf[64];
    __shared__ float vbuf[64];

    const int b = blockIdx.x;
    const int wave = threadIdx.x >> 6;
    const int lane = threadIdx.x & 63;
    const bool act = lane < NK;
    const int LL = act ? lane : (NK - 1);
    const float* f = feats + (size_t)b * NT * NK;
    const float* fb = f + LL;

    float tEnd = NEGV;
    if (act && lane != S_END) tEnd = trans[S_END * NK + lane];

    if (wave == 0) {
        float Erow[NK];
        {
            const bool rowdead = (lane == S_START);
            const float4* r4 = (const float4*)(trans + LL * NK);
            #pragma unroll
            for (int q = 0; q < NK / 4; ++q) {
                float4 r = r4[q];
                const int c = 4 * q;
                Erow[c + 0] = (rowdead || c + 0 == S_END) ? 0.0f : __expf(r.x);
                Erow[c + 1] = (rowdead || c + 1 == S_END) ? 0.0f : __expf(r.y);
                Erow[c + 2] = (rowdead || c + 2 == S_END) ? 0.0f : __expf(r.z);
                Erow[c + 3] = (rowdead || c + 3 == S_END) ? 0.0f : __expf(r.w);
            }
        }
        float u = (lane == S_START) ? 0.0f : NEGV;
        float Muni = 0.0f;
        eabuf[lane] = __expf(u);
        __builtin_amdgcn_wave_barrier();
        float fr0 = fb[0 * NK], fr1 = fb[1 * NK], fr2 = fb[2 * NK], fr3 = fb[3 * NK];

        auto fstep = [&](float fc) {
            float ea[NK];
            {
                const float4* e4 = (const float4*)eabuf;
                #pragma unroll
                for (int q = 0; q < NK / 4; ++q) {
                    float4 r = e4[q];
                    ea[4 * q + 0] = r.x; ea[4 * q + 1] = r.y;
                    ea[4 * q + 2] = r.z; ea[4 * q + 3] = r.w;
                }
            }
            float a0 = 0.f, a1 = 0.f, a2 = 0.f, a3 = 0.f;
            #pragma unroll
            for (int p = 0; p < NK; p += 4) {
                a0 = fmaf(Erow[p + 0], ea[p + 0], a0);
                a1 = fmaf(Erow[p + 1], ea[p + 1], a1);
                a2 = fmaf(Erow[p + 2], ea[p + 2], a2);
                a3 = fmaf(Erow[p + 3], ea[p + 3], a3);
            }
            float acc = (a0 + a1) + (a2 + a3);
            float w = __logf(acc) + fc;
            float dM = rfl_f32(w);
            Muni += dM;
            u = w - dM;
            __builtin_amdgcn_wave_barrier();
            eabuf[lane] = __expf(u);
            __builtin_amdgcn_wave_barrier();
        };

        for (int t = 0; t < NT; t += 4) {
            { float fc = fr0; int nr = (t + 4 < NT) ? t + 4 : NT - 1; fr0 = fb[nr * NK]; fstep(fc); }
            { float fc = fr1; int nr = (t + 5 < NT) ? t + 5 : NT - 1; fr1 = fb[nr * NK]; fstep(fc); }
            { float fc = fr2; int nr = (t + 6 < NT) ? t + 6 : NT - 1; fr2 = fb[nr * NK]; fstep(fc); }
            { float fc = fr3; int nr = (t + 7 < NT) ? t + 7 : NT - 1; fr3 = fb[nr * NK]; fstep(fc); }
        }
        float x = act ? (u + tEnd) : -INFINITY;
        float M2 = x;
        #pragma unroll
        for (int off = 32; off >= 1; off >>= 1)
            M2 = fmaxf(M2, __shfl_xor(M2, off, 64));
        float e = __expf(x - M2);
        #pragma unroll
        for (int off = 32; off >= 1; off >>= 1)
            e += __shfl_xor(e, off, 64);
        if (lane == 0) out[b] = Muni + M2 + __logf(e);
    } else {
        float trow[NK];
        {
            const bool rowdead = (lane == S_START);
            const float4* r4 = (const float4*)(trans + LL * NK);
            #pragma unroll
            for (int q = 0; q < NK / 4; ++q) {
                float4 r = r4[q];
                const int c = 4 * q;
                trow[c + 0] = (rowdead || c + 0 == S_END) ? NEGV : r.x;
                trow[c + 1] = (rowdead || c + 1 == S_END) ? NEGV : r.y;
                trow[c + 2] = (rowdead || c + 2 == S_END) ? NEGV : r.z;
                trow[c + 3] = (rowdead || c + 3 == S_END) ? NEGV : r.w;
            }
        }
        float v = (lane == S_START) ? 0.0f : NEGV;
        vbuf[lane] = v;
        __builtin_amdgcn_wave_barrier();
        float fr0 = fb[0 * NK], fr1 = fb[1 * NK], fr2 = fb[2 * NK], fr3 = fb[3 * NK];
        const int big = 63;

        auto vstep = [&](float fc, int tt) {
            float s[NK];
            {
                const float4* v4 = (const float4*)vbuf;
                #pragma unroll
                for (int q = 0; q < NK / 4; ++q) {
                    float4 r = v4[q];
                    s[4 * q + 0] = r.x + trow[4 * q + 0];
                    s[4 * q + 1] = r.y + trow[4 * q + 1];
                    s[4 * q + 2] = r.z + trow[4 * q + 2];
                    s[4 * q + 3] = r.w + trow[4 * q + 3];
                }
            }
            float m16[16];
            #pragma unroll
            for (int i = 0; i < 16; ++i)
                m16[i] = fmaxf(fmaxf(s[3 * i], s[3 * i + 1]), s[3 * i + 2]);
            float m6[6];
            #pragma unroll
            for (int i = 0; i < 5; ++i)
                m6[i] = fmaxf(fmaxf(m16[3 * i], m16[3 * i + 1]), m16[3 * i + 2]);
            m6[5] = m16[15];
            float best = fmaxf(fmaxf(fmaxf(m6[0], m6[1]), m6[2]),
                               fmaxf(fmaxf(m6[3], m6[4]), m6[5]));
            v = best + fc;
            __builtin_amdgcn_wave_barrier();
            vbuf[lane] = v;
            __builtin_amdgcn_wave_barrier();
            int ix[NK];
            #pragma unroll
            for (int p = 0; p < NK; ++p)
                ix[p] = (s[p] != best) ? big : p;
            int n16[16];
            #pragma unroll
            for (int i = 0; i < 16; ++i)
                n16[i] = min(min(ix[3 * i], ix[3 * i + 1]), ix[3 * i + 2]);
            int n6[6];
            #pragma unroll
            for (int i = 0; i < 5; ++i)
                n6[i] = min(min(n16[3 * i], n16[3 * i + 1]), n16[3 * i + 2]);
            n6[5] = n16[15];
            int bi = min(min(min(n6[0], n6[1]), n6[2]),
                         min(min(n6[3], n6[4]), n6[5]));
            bp[tt * NK + LL] = (unsigned char)bi;
        };

        for (int t = 0; t < NT; t += 4) {
            { float fc = fr0; int nr = (t + 4 < NT) ? t + 4 : NT - 1; fr0 = fb[nr * NK]; vstep(fc, t + 0); }
            { float fc = fr1; int nr = (t + 5 < NT) ? t + 5 : NT - 1; fr1 = fb[nr * NK]; vstep(fc, t + 1); }
            { float fc = fr2; int nr = (t + 6 < NT) ? t + 6 : NT - 1; fr2 = fb[nr * NK]; vstep(fc, t + 2); }
            { float fc = fr3; int nr = (t + 7 < NT) ? t + 7 : NT - 1; fr3 = fb[nr * NK]; vstep(fc, t + 3); }
        }
        float xv = act ? (v + tEnd) : -INFINITY;
        int idx = act ? lane : 63;
        float val = xv;
        #pragma unroll
        for (int off = 32; off >= 1; off >>= 1) {
            float ov = __shfl_xor(val, off, 64);
            int   oi = __shfl_xor(idx, off, 64);
            if (ov > val || (ov == val && oi < idx)) { val = ov; idx = oi; }
        }
        if (lane == 0) out[NB + b] = val;
        const int last = idx;

        __builtin_amdgcn_wave_barrier();
        int cur[NK];
        #pragma unroll
        for (int k = 0; k < NK; ++k) cur[k] = k;
        const int tbase = lane * 16;
        for (int i = 15; i >= 0; --i) {
            const int t = tbase + i;
            #pragma unroll
            for (int k = 0; k < NK; ++k) cur[k] = bp[t * NK + cur[k]];
        }
        #pragma unroll
        for (int k = 0; k < NK; ++k) comp[lane * NK + k] = (unsigned char)cur[k];
        __builtin_amdgcn_wave_barrier();

        if (lane == 0) {
            int tag = last;
            for (int l = 63; l >= 0; --l) {
                boundary[l] = (unsigned char)tag;
                tag = comp[l * NK + tag];
            }
        }
        __builtin_amdgcn_wave_barrier();

        int tag = boundary[lane];
        float* pout = out + 2 * NB + (size_t)b * NT;
        for (int i = 15; i >= 0; --i) {
            const int t = tbase + i;
            pout[t] = (float)tag;
            tag = bp[t * NK + tag];
        }
    }
}

extern "C" void kernel_launch(void* const* d_in, const int* in_sizes, int n_in,
                              void* d_out, int out_size, void* d_ws, size_t ws_size,
                              hipStream_t stream) {
    (void)in_sizes; (void)n_in; (void)out_size;
    const float* feats = (const float*)d_in[0];
    const float* trans = (const float*)d_in[1];
    float* out = (float*)d_out;
    if (d_ws != nullptr && ws_size >= WS_BP_SZ) {
        crf_pipe<<<dim3(NB), dim3(256), 0, stream>>>(feats, trans, out,
                                                     (unsigned char*)d_ws);
    } else {
        crf_fused_fb<<<dim3(NB), dim3(128), 0, stream>>>(feats, trans, out);
    }
}